// Round 8
// baseline (184.207 us; speedup 1.0000x reference)
//
#include <hip/hip_runtime.h>
#include <hip/hip_bf16.h>

// GlobalPoolDistance: RBF-kernel MMD over 3x3 patch unfolds (8,3,64,64) f32.
// N = 62*62 = 3844 patches, d = 27 (padded K=32). SIG2 = 0.2916.
// R8: BARRIER-FREE pairs kernel. R5-R7 evidence: 2-barrier lockstep blocks
// ran at <= serial speed (132k cyc/CU vs 93k serial pipe work, occupancy 31%,
// VGPR stuck at 64). Now each WAVE is an independent 128x128 tile job:
// A-frags (8 hi/lo) in registers for the job, B-frags streamed from global
// (L2-resident, ~500MB total through L1/L2 ~ 20 TB/s < 34.5 ceiling), no LDS,
// no syncthreads. 15624 wave-jobs / 3906 blocks, m204 bijective XCD swizzle,
// panel-major job order for L2 locality.
// Recap: p-terms baked into MFMA pad cols (MFMA out IS the exp2 arg, epilogue
// = exp2+add), split-bf16 3-MFMA gram, xx/yy upper-tri symmetry (off-diag x2).
//
// ws: Ah|Al|Bh|Bl [16][3968][32] bf16 (4 x 4,063,232 B) + acc[32] f32.

#define NP    3844
#define NPAD  3968
#define KP    32

#define W_XY  7688     // 8 * 31 * 31  xy wave-jobs
#define W_ALL 15624    // + 2 * 8 * 496 tri wave-jobs
#define NBLK  3906     // W_ALL / 4 waves per block

static constexpr float L_F   = 4.9475824173972215f;   // log2(e)/0.2916
static constexpr float C2L_F = 9.895164834794443f;    // 2*L

using bf16x8 = __attribute__((ext_vector_type(8))) short;
using f32x4  = __attribute__((ext_vector_type(4))) float;

#define MFMA16(a, b, c) __builtin_amdgcn_mfma_f32_16x16x32_bf16((a), (b), (c), 0, 0, 0)

__device__ inline unsigned short f2bf(float f) {
    union { float f; unsigned u; } v; v.f = f;
    unsigned r = v.u + 0x7FFFu + ((v.u >> 16) & 1u);   // RNE (no NaN inputs)
    return (unsigned short)(r >> 16);
}
__device__ inline float bf2f(unsigned short h) {
    union { unsigned u; float f; } v; v.u = ((unsigned)h) << 16;
    return v.f;
}
__device__ inline void pack_store(unsigned short* dst, const unsigned short* v) {
    uint4* d = (uint4*)dst;
#pragma unroll
    for (int q = 0; q < 4; ++q) {
        unsigned w0 = (unsigned)v[8 * q + 0] | ((unsigned)v[8 * q + 1] << 16);
        unsigned w1 = (unsigned)v[8 * q + 2] | ((unsigned)v[8 * q + 3] << 16);
        unsigned w2 = (unsigned)v[8 * q + 4] | ((unsigned)v[8 * q + 5] << 16);
        unsigned w3 = (unsigned)v[8 * q + 6] | ((unsigned)v[8 * q + 7] << 16);
        d[q] = make_uint4(w0, w1, w2, w3);
    }
}

// One thread per (im, patch). A-side scaled by 2L with p-cols; B-side plain.
__global__ __launch_bounds__(256) void gp_prep(const float* __restrict__ x,
                                               const float* __restrict__ y,
                                               unsigned short* __restrict__ Ah,
                                               unsigned short* __restrict__ Al,
                                               unsigned short* __restrict__ Bh,
                                               unsigned short* __restrict__ Bl,
                                               float* __restrict__ acc) {
    if (blockIdx.x == 0 && threadIdx.x < 32) acc[threadIdx.x] = 0.0f;
    int i = blockIdx.x * 256 + threadIdx.x;          // 16*NPAD = 63488
    if (i >= 16 * NPAD) return;
    int n = i % NPAD, im = i / NPAD;
    int b = im & 7;
    const float* src = (im >> 3) ? y : x;

    unsigned short hA[32], lA[32], hB[32], lB[32];
#pragma unroll
    for (int k = 0; k < 32; ++k) { hA[k] = 0; lA[k] = 0; hB[k] = 0; lB[k] = 0; }

    float sq = 0.0f;
    const bool valid = (n < NP);
    if (valid) {
        int r = n / 62, c = n % 62;
#pragma unroll
        for (int ch = 0; ch < 3; ++ch)
#pragma unroll
            for (int pr = 0; pr < 3; ++pr)
#pragma unroll
                for (int pc = 0; pc < 3; ++pc) {
                    int k = ch * 9 + pr * 3 + pc;
                    float v = src[(((b * 3 + ch) * 64) + r + pr) * 64 + (c + pc)];
                    unsigned short hb = f2bf(v);
                    hB[k] = hb; lB[k] = f2bf(v - bf2f(hb));
                    float sv = C2L_F * v;
                    unsigned short ha = f2bf(sv);
                    hA[k] = ha; lA[k] = f2bf(sv - bf2f(ha));
                    sq = fmaf(v, v, sq);
                }
    }
    // col 27: A = 2L (const), B = -sq/2 (pad: -1e30 -> exp2 -> 0)
    {
        unsigned short h = f2bf(C2L_F);
        hA[27] = h; lA[27] = f2bf(C2L_F - bf2f(h));
        float tb = valid ? -0.5f * sq : -1e30f;
        unsigned short hb = f2bf(tb);
        hB[27] = hb; lB[27] = f2bf(tb - bf2f(hb));
    }
    // col 28: A = -L*sq (pad: -1e30), B = 1
    {
        float pa = valid ? -L_F * sq : -1e30f;
        unsigned short ha = f2bf(pa);
        hA[28] = ha; lA[28] = f2bf(pa - bf2f(ha));
        hB[28] = f2bf(1.0f); lB[28] = 0;
    }

    pack_store(Ah + (size_t)i * KP, hA);
    pack_store(Al + (size_t)i * KP, lA);
    pack_store(Bh + (size_t)i * KP, hB);
    pack_store(Bl + (size_t)i * KP, lB);
}

// Barrier-free pairs: one 128x128 tile per WAVE, fragments from global.
// Job order (panel-major): xy jobs (b, by, bx) then tri jobs (type, b, by,
// bx<=by) -- consecutive jobs share the B column-panel (L1/L2 temporal
// locality). m204 bijective XCD swizzle on blocks: nwg=3906=8*488+2.
__global__ __launch_bounds__(256, 4) void gp_pairs8(const unsigned short* __restrict__ Ah,
                                                    const unsigned short* __restrict__ Al,
                                                    const unsigned short* __restrict__ Bh,
                                                    const unsigned short* __restrict__ Bl,
                                                    float* __restrict__ acc) {
    const int phys = blockIdx.x;
    const int xcd = phys & 7, oi = phys >> 3;
    const int blk = (xcd < 2 ? xcd * 489 : 2 * 489 + (xcd - 2) * 488) + oi;

    const int t = threadIdx.x;
    const int wv = t >> 6, l = t & 63, l15 = l & 15, lhi = l >> 4;
    const int w = blk * 4 + wv;            // wave-job id, < 15624

    int type, b, bx, by;
    float wt = 1.0f;
    if (w < W_XY) {
        type = 0; b = w / 961;
        int rr = w % 961; by = rr / 31; bx = rr % 31;
    } else {
        int v = w - W_XY;
        type = 1 + v / 3968;
        int r = v % 3968; b = r / 496; int t2 = r % 496;
        by = (int)((sqrtf(8.0f * (float)t2 + 1.0f) - 1.0f) * 0.5f);
        while ((by + 1) * (by + 2) / 2 <= t2) ++by;
        while (by * (by + 1) / 2 > t2) --by;
        bx = t2 - by * (by + 1) / 2;
        wt = (bx == by) ? 1.0f : 2.0f;
    }
    int imA, imB;
    if (type == 0)      { imA = b;     imB = 8 + b; }
    else if (type == 1) { imA = b;     imB = b;     }
    else                { imA = 8 + b; imB = 8 + b; }

    // A fragments for the whole job: 128 rows (8 x hi/lo), 64 VGPR.
    bf16x8 ah[8], al[8];
#pragma unroll
    for (int rg = 0; rg < 8; ++rg) {
        size_t e = ((size_t)(imA * NPAD + bx * 128 + rg * 16 + l15)) * KP + lhi * 8;
        ah[rg] = *(const bf16x8*)(Ah + e);
        al[rg] = *(const bf16x8*)(Al + e);
    }

    float s0 = 0.f, s1 = 0.f, s2 = 0.f, s3 = 0.f;
#pragma unroll
    for (int cg = 0; cg < 8; ++cg) {
        size_t e = ((size_t)(imB * NPAD + by * 128 + cg * 16 + l15)) * KP + lhi * 8;
        const bf16x8 bhc = *(const bf16x8*)(Bh + e);
        const bf16x8 blc = *(const bf16x8*)(Bl + e);
#pragma unroll
        for (int h = 0; h < 2; ++h) {
            // four independent rg-chains in flight sharing bhc/blc
            const int r0 = h * 4;
            f32x4 g0 = {0.f, 0.f, 0.f, 0.f};
            f32x4 g1 = {0.f, 0.f, 0.f, 0.f};
            f32x4 g2 = {0.f, 0.f, 0.f, 0.f};
            f32x4 g3 = {0.f, 0.f, 0.f, 0.f};
            g0 = MFMA16(al[r0 + 0], bhc, g0);
            g1 = MFMA16(al[r0 + 1], bhc, g1);
            g2 = MFMA16(al[r0 + 2], bhc, g2);
            g3 = MFMA16(al[r0 + 3], bhc, g3);
            g0 = MFMA16(ah[r0 + 0], blc, g0);
            g1 = MFMA16(ah[r0 + 1], blc, g1);
            g2 = MFMA16(ah[r0 + 2], blc, g2);
            g3 = MFMA16(ah[r0 + 3], blc, g3);
            g0 = MFMA16(ah[r0 + 0], bhc, g0);
            g1 = MFMA16(ah[r0 + 1], bhc, g1);
            g2 = MFMA16(ah[r0 + 2], bhc, g2);
            g3 = MFMA16(ah[r0 + 3], bhc, g3);
            s0 += __builtin_amdgcn_exp2f(g0[0]);
            s1 += __builtin_amdgcn_exp2f(g0[1]);
            s2 += __builtin_amdgcn_exp2f(g0[2]);
            s3 += __builtin_amdgcn_exp2f(g0[3]);
            s0 += __builtin_amdgcn_exp2f(g1[0]);
            s1 += __builtin_amdgcn_exp2f(g1[1]);
            s2 += __builtin_amdgcn_exp2f(g1[2]);
            s3 += __builtin_amdgcn_exp2f(g1[3]);
            s0 += __builtin_amdgcn_exp2f(g2[0]);
            s1 += __builtin_amdgcn_exp2f(g2[1]);
            s2 += __builtin_amdgcn_exp2f(g2[2]);
            s3 += __builtin_amdgcn_exp2f(g2[3]);
            s0 += __builtin_amdgcn_exp2f(g3[0]);
            s1 += __builtin_amdgcn_exp2f(g3[1]);
            s2 += __builtin_amdgcn_exp2f(g3[2]);
            s3 += __builtin_amdgcn_exp2f(g3[3]);
        }
    }
    float sacc = wt * ((s0 + s1) + (s2 + s3));

    // wave reduce, one atomic per wave (15624 atomics over 24 cells -- fine)
#pragma unroll
    for (int o = 32; o > 0; o >>= 1) sacc += __shfl_down(sacc, o, 64);
    if (l == 0) atomicAdd(&acc[type * 8 + b], sacc);
}

__global__ void gp_final(const float* __restrict__ acc, float* __restrict__ out) {
    if (threadIdx.x == 0) {
        double s = 0.0;
        for (int b = 0; b < 8; ++b)
            s += -2.0 * (double)acc[b] + (double)acc[8 + b] + (double)acc[16 + b];
        out[0] = (float)(s / (8.0 * (double)NP * (double)NP));
    }
}

extern "C" void kernel_launch(void* const* d_in, const int* in_sizes, int n_in,
                              void* d_out, int out_size, void* d_ws, size_t ws_size,
                              hipStream_t stream) {
    const float* x = (const float*)d_in[0];
    const float* y = (const float*)d_in[1];
    const size_t MSZ = (size_t)16 * NPAD * KP;
    unsigned short* Ah = (unsigned short*)d_ws;
    unsigned short* Al = Ah + MSZ;
    unsigned short* Bh = Al + MSZ;
    unsigned short* Bl = Bh + MSZ;
    float* acc = (float*)(Bl + MSZ);

    gp_prep<<<(16 * NPAD) / 256, 256, 0, stream>>>(x, y, Ah, Al, Bh, Bl, acc);
    gp_pairs8<<<NBLK, 256, 0, stream>>>(Ah, Al, Bh, Bl, acc);
    gp_final<<<1, 1, 0, stream>>>(acc, (float*)d_out);
}

// Round 9
// 181.892 us; speedup vs baseline: 1.0127x; 1.0127x over previous
//
#include <hip/hip_runtime.h>
#include <hip/hip_bf16.h>

// GlobalPoolDistance: RBF-kernel MMD over 3x3 patch unfolds (8,3,64,64) f32.
// N = 62*62 = 3844 patches, d = 27 (padded K=32). SIG2 = 0.2916.
// R9: barrier-free one-wave 128x128 tile jobs with ALL global loads in
// inline asm + manual counted vmcnt (AITER protocol). R8 evidence: compiler
// sank/remat'd A-frag loads (VGPR 52 < the 64 the A-frags need) ->
// latency-serialized at 165us. asm loads are opaque: cannot be sunk, "+v"
// waitcnt ties pin them in registers. sched_barrier(0) after each wait
// (guide rule 18). One wave per block (64 thr), no LDS, no barriers.
// Recap: p-terms baked in MFMA pad cols (MFMA out IS the exp2 arg),
// split-bf16 3-MFMA gram, xx/yy triangle symmetry, panel-major job order,
// 8x1953 bijective XCD swizzle.
//
// ws: Ah|Al|Bh|Bl [16][3968][32] bf16 (4 x 4,063,232 B) + acc[32] f32.

#define NP    3844
#define NPAD  3968
#define KP    32

#define W_XY  7688     // 8 * 31 * 31  xy wave-jobs
#define W_ALL 15624    // + 2 * 8 * 496 tri wave-jobs; 15624 = 8 * 1953
#define NBLK  15624

static constexpr float L_F   = 4.9475824173972215f;   // log2(e)/0.2916
static constexpr float C2L_F = 9.895164834794443f;    // 2*L

using bf16x8 = __attribute__((ext_vector_type(8))) short;
using f32x4  = __attribute__((ext_vector_type(4))) float;

#define MFMA16(a, b, c) __builtin_amdgcn_mfma_f32_16x16x32_bf16((a), (b), (c), 0, 0, 0)

__device__ inline unsigned short f2bf(float f) {
    union { float f; unsigned u; } v; v.f = f;
    unsigned r = v.u + 0x7FFFu + ((v.u >> 16) & 1u);   // RNE (no NaN inputs)
    return (unsigned short)(r >> 16);
}
__device__ inline float bf2f(unsigned short h) {
    union { unsigned u; float f; } v; v.u = ((unsigned)h) << 16;
    return v.f;
}
__device__ inline void pack_store(unsigned short* dst, const unsigned short* v) {
    uint4* d = (uint4*)dst;
#pragma unroll
    for (int q = 0; q < 4; ++q) {
        unsigned w0 = (unsigned)v[8 * q + 0] | ((unsigned)v[8 * q + 1] << 16);
        unsigned w1 = (unsigned)v[8 * q + 2] | ((unsigned)v[8 * q + 3] << 16);
        unsigned w2 = (unsigned)v[8 * q + 4] | ((unsigned)v[8 * q + 5] << 16);
        unsigned w3 = (unsigned)v[8 * q + 6] | ((unsigned)v[8 * q + 7] << 16);
        d[q] = make_uint4(w0, w1, w2, w3);
    }
}

// One thread per (im, patch). A-side scaled by 2L with p-cols; B-side plain.
__global__ __launch_bounds__(256) void gp_prep(const float* __restrict__ x,
                                               const float* __restrict__ y,
                                               unsigned short* __restrict__ Ah,
                                               unsigned short* __restrict__ Al,
                                               unsigned short* __restrict__ Bh,
                                               unsigned short* __restrict__ Bl,
                                               float* __restrict__ acc) {
    if (blockIdx.x == 0 && threadIdx.x < 32) acc[threadIdx.x] = 0.0f;
    int i = blockIdx.x * 256 + threadIdx.x;          // 16*NPAD = 63488
    if (i >= 16 * NPAD) return;
    int n = i % NPAD, im = i / NPAD;
    int b = im & 7;
    const float* src = (im >> 3) ? y : x;

    unsigned short hA[32], lA[32], hB[32], lB[32];
#pragma unroll
    for (int k = 0; k < 32; ++k) { hA[k] = 0; lA[k] = 0; hB[k] = 0; lB[k] = 0; }

    float sq = 0.0f;
    const bool valid = (n < NP);
    if (valid) {
        int r = n / 62, c = n % 62;
#pragma unroll
        for (int ch = 0; ch < 3; ++ch)
#pragma unroll
            for (int pr = 0; pr < 3; ++pr)
#pragma unroll
                for (int pc = 0; pc < 3; ++pc) {
                    int k = ch * 9 + pr * 3 + pc;
                    float v = src[(((b * 3 + ch) * 64) + r + pr) * 64 + (c + pc)];
                    unsigned short hb = f2bf(v);
                    hB[k] = hb; lB[k] = f2bf(v - bf2f(hb));
                    float sv = C2L_F * v;
                    unsigned short ha = f2bf(sv);
                    hA[k] = ha; lA[k] = f2bf(sv - bf2f(ha));
                    sq = fmaf(v, v, sq);
                }
    }
    // col 27: A = 2L (const), B = -sq/2 (pad: -1e30 -> exp2 -> 0)
    {
        unsigned short h = f2bf(C2L_F);
        hA[27] = h; lA[27] = f2bf(C2L_F - bf2f(h));
        float tb = valid ? -0.5f * sq : -1e30f;
        unsigned short hb = f2bf(tb);
        hB[27] = hb; lB[27] = f2bf(tb - bf2f(hb));
    }
    // col 28: A = -L*sq (pad: -1e30), B = 1
    {
        float pa = valid ? -L_F * sq : -1e30f;
        unsigned short ha = f2bf(pa);
        hA[28] = ha; lA[28] = f2bf(pa - bf2f(ha));
        hB[28] = f2bf(1.0f); lB[28] = 0;
    }

    pack_store(Ah + (size_t)i * KP, hA);
    pack_store(Al + (size_t)i * KP, lA);
    pack_store(Bh + (size_t)i * KP, hB);
    pack_store(Bl + (size_t)i * KP, lB);
}

// Opaque 16B global load with immediate offset: cannot be sunk or remat'd.
template<int OFF>
__device__ inline bf16x8 gload(const unsigned short* p) {
    bf16x8 r;
    asm volatile("global_load_dwordx4 %0, %1, off offset:%2"
                 : "=v"(r) : "v"(p), "i"(OFF));
    return r;
}

// 4 independent rg-chains sharing one B fragment, then 16 exp2+add.
#define GROUP(AH0, AH1, AH2, AH3, AL0, AL1, AL2, AL3, BHC, BLC)              \
    do {                                                                     \
        f32x4 g0 = {0.f, 0.f, 0.f, 0.f}, g1 = {0.f, 0.f, 0.f, 0.f};          \
        f32x4 g2 = {0.f, 0.f, 0.f, 0.f}, g3 = {0.f, 0.f, 0.f, 0.f};          \
        g0 = MFMA16(AL0, BHC, g0); g1 = MFMA16(AL1, BHC, g1);                \
        g2 = MFMA16(AL2, BHC, g2); g3 = MFMA16(AL3, BHC, g3);                \
        g0 = MFMA16(AH0, BLC, g0); g1 = MFMA16(AH1, BLC, g1);                \
        g2 = MFMA16(AH2, BLC, g2); g3 = MFMA16(AH3, BLC, g3);                \
        g0 = MFMA16(AH0, BHC, g0); g1 = MFMA16(AH1, BHC, g1);                \
        g2 = MFMA16(AH2, BHC, g2); g3 = MFMA16(AH3, BHC, g3);                \
        s0 += __builtin_amdgcn_exp2f(g0[0]); s1 += __builtin_amdgcn_exp2f(g0[1]); \
        s2 += __builtin_amdgcn_exp2f(g0[2]); s3 += __builtin_amdgcn_exp2f(g0[3]); \
        s0 += __builtin_amdgcn_exp2f(g1[0]); s1 += __builtin_amdgcn_exp2f(g1[1]); \
        s2 += __builtin_amdgcn_exp2f(g1[2]); s3 += __builtin_amdgcn_exp2f(g1[3]); \
        s0 += __builtin_amdgcn_exp2f(g2[0]); s1 += __builtin_amdgcn_exp2f(g2[1]); \
        s2 += __builtin_amdgcn_exp2f(g2[2]); s3 += __builtin_amdgcn_exp2f(g2[3]); \
        s0 += __builtin_amdgcn_exp2f(g3[0]); s1 += __builtin_amdgcn_exp2f(g3[1]); \
        s2 += __builtin_amdgcn_exp2f(g3[2]); s3 += __builtin_amdgcn_exp2f(g3[3]); \
    } while (0)

// step: issue next B pair (opaque), wait current pair (counted, tied via +v),
// then compute both rg halves against the current pair.
#define STEP_MID(BHC, BLC, BHN, BLN, PH, PL, OFFN)                           \
    do {                                                                     \
        BHN = gload<OFFN>(PH); BLN = gload<OFFN>(PL);                        \
        asm volatile("s_waitcnt vmcnt(2)" : "+v"(BHC), "+v"(BLC));           \
        __builtin_amdgcn_sched_barrier(0);                                   \
        GROUP(ah0, ah1, ah2, ah3, al0, al1, al2, al3, BHC, BLC);             \
        GROUP(ah4, ah5, ah6, ah7, al4, al5, al6, al7, BHC, BLC);             \
    } while (0)

#define STEP_LAST(BHC, BLC)                                                  \
    do {                                                                     \
        asm volatile("s_waitcnt vmcnt(0)" : "+v"(BHC), "+v"(BLC));           \
        __builtin_amdgcn_sched_barrier(0);                                   \
        GROUP(ah0, ah1, ah2, ah3, al0, al1, al2, al3, BHC, BLC);             \
        GROUP(ah4, ah5, ah6, ah7, al4, al5, al6, al7, BHC, BLC);             \
    } while (0)

__global__ __launch_bounds__(64, 4) void gp_pairs9(const unsigned short* __restrict__ Ah,
                                                   const unsigned short* __restrict__ Al,
                                                   const unsigned short* __restrict__ Bh,
                                                   const unsigned short* __restrict__ Bl,
                                                   float* __restrict__ acc) {
    const int phys = blockIdx.x;
    const int w = (phys & 7) * 1953 + (phys >> 3);   // bijective, 15624 = 8*1953

    const int l = threadIdx.x & 63;
    const int l15 = l & 15, lhi = l >> 4;

    int type, b, bx, by;
    float wt = 1.0f;
    if (w < W_XY) {
        type = 0; b = w / 961;
        int rr = w % 961; by = rr / 31; bx = rr % 31;
    } else {
        int v = w - W_XY;
        type = 1 + v / 3968;
        int r = v % 3968; b = r / 496; int t2 = r % 496;
        by = (int)((sqrtf(8.0f * (float)t2 + 1.0f) - 1.0f) * 0.5f);
        while ((by + 1) * (by + 2) / 2 <= t2) ++by;
        while (by * (by + 1) / 2 > t2) --by;
        bx = t2 - by * (by + 1) / 2;
        wt = (bx == by) ? 1.0f : 2.0f;
    }
    int imA, imB;
    if (type == 0)      { imA = b;     imB = 8 + b; }
    else if (type == 1) { imA = b;     imB = b;     }
    else                { imA = 8 + b; imB = 8 + b; }

    // base pointers (rg/cg 0-3 via offset 0..3072; 4-7 via +4096B base)
    const size_t eA = ((size_t)(imA * NPAD + bx * 128 + l15)) * KP + lhi * 8;
    const size_t eB = ((size_t)(imB * NPAD + by * 128 + l15)) * KP + lhi * 8;
    const unsigned short* pAh0 = Ah + eA;
    const unsigned short* pAl0 = Al + eA;
    const unsigned short* pAh4 = pAh0 + 2048;
    const unsigned short* pAl4 = pAl0 + 2048;
    const unsigned short* pBh0 = Bh + eB;
    const unsigned short* pBl0 = Bl + eB;
    const unsigned short* pBh4 = pBh0 + 2048;
    const unsigned short* pBl4 = pBl0 + 2048;

    // A fragments: 16 opaque loads, pinned for the whole job (64 VGPR).
    bf16x8 ah0 = gload<0>(pAh0),    ah1 = gload<1024>(pAh0);
    bf16x8 ah2 = gload<2048>(pAh0), ah3 = gload<3072>(pAh0);
    bf16x8 ah4 = gload<0>(pAh4),    ah5 = gload<1024>(pAh4);
    bf16x8 ah6 = gload<2048>(pAh4), ah7 = gload<3072>(pAh4);
    bf16x8 al0 = gload<0>(pAl0),    al1 = gload<1024>(pAl0);
    bf16x8 al2 = gload<2048>(pAl0), al3 = gload<3072>(pAl0);
    bf16x8 al4 = gload<0>(pAl4),    al5 = gload<1024>(pAl4);
    bf16x8 al6 = gload<2048>(pAl4), al7 = gload<3072>(pAl4);

    // first B pair in flight before the A-wait
    bf16x8 bhA = gload<0>(pBh0), blA = gload<0>(pBl0);
    bf16x8 bhB, blB;

    // wait A (leave the 2 B loads outstanding), pin all 16 A regs
    asm volatile("s_waitcnt vmcnt(2)"
                 : "+v"(ah0), "+v"(ah1), "+v"(ah2), "+v"(ah3),
                   "+v"(ah4), "+v"(ah5), "+v"(ah6), "+v"(ah7),
                   "+v"(al0), "+v"(al1), "+v"(al2), "+v"(al3),
                   "+v"(al4), "+v"(al5), "+v"(al6), "+v"(al7));
    __builtin_amdgcn_sched_barrier(0);

    float s0 = 0.f, s1 = 0.f, s2 = 0.f, s3 = 0.f;

    STEP_MID(bhA, blA, bhB, blB, pBh0, pBl0, 1024);   // cg0 (issue cg1)
    STEP_MID(bhB, blB, bhA, blA, pBh0, pBl0, 2048);   // cg1 (issue cg2)
    STEP_MID(bhA, blA, bhB, blB, pBh0, pBl0, 3072);   // cg2 (issue cg3)
    STEP_MID(bhB, blB, bhA, blA, pBh4, pBl4, 0);      // cg3 (issue cg4)
    STEP_MID(bhA, blA, bhB, blB, pBh4, pBl4, 1024);   // cg4 (issue cg5)
    STEP_MID(bhB, blB, bhA, blA, pBh4, pBl4, 2048);   // cg5 (issue cg6)
    STEP_MID(bhA, blA, bhB, blB, pBh4, pBl4, 3072);   // cg6 (issue cg7)
    STEP_LAST(bhB, blB);                              // cg7

    float sacc = wt * ((s0 + s1) + (s2 + s3));

    // wave reduce, one atomic per wave (15624 atomics over 24 cells)
#pragma unroll
    for (int o = 32; o > 0; o >>= 1) sacc += __shfl_down(sacc, o, 64);
    if (l == 0) atomicAdd(&acc[type * 8 + b], sacc);
}

__global__ void gp_final(const float* __restrict__ acc, float* __restrict__ out) {
    if (threadIdx.x == 0) {
        double s = 0.0;
        for (int b = 0; b < 8; ++b)
            s += -2.0 * (double)acc[b] + (double)acc[8 + b] + (double)acc[16 + b];
        out[0] = (float)(s / (8.0 * (double)NP * (double)NP));
    }
}

extern "C" void kernel_launch(void* const* d_in, const int* in_sizes, int n_in,
                              void* d_out, int out_size, void* d_ws, size_t ws_size,
                              hipStream_t stream) {
    const float* x = (const float*)d_in[0];
    const float* y = (const float*)d_in[1];
    const size_t MSZ = (size_t)16 * NPAD * KP;
    unsigned short* Ah = (unsigned short*)d_ws;
    unsigned short* Al = Ah + MSZ;
    unsigned short* Bh = Al + MSZ;
    unsigned short* Bl = Bh + MSZ;
    float* acc = (float*)(Bl + MSZ);

    gp_prep<<<(16 * NPAD) / 256, 256, 0, stream>>>(x, y, Ah, Al, Bh, Bl, acc);
    gp_pairs9<<<NBLK, 64, 0, stream>>>(Ah, Al, Bh, Bl, acc);
    gp_final<<<1, 1, 0, stream>>>(acc, (float*)d_out);
}

// Round 10
// 69.462 us; speedup vs baseline: 2.6519x; 2.6186x over previous
//
#include <hip/hip_runtime.h>
#include <hip/hip_bf16.h>

// GlobalPoolDistance: RBF-kernel MMD over 3x3 patch unfolds (8,3,64,64) f32.
// N = 62*62 = 3844 patches, d = 27 (padded K=32). SIG2 = 0.2916.
// R10 = R9 with the contended atomics REMOVED (the isolated change).
// Evidence: R2/R8/R9 (15624 same-line atomicAdds) all ~161-182us despite
// totally different compute structures; 161us = 15624 x ~25cyc = same-line
// device-atomic service rate gating wave retirement. Now each wave stores its
// partial to a UNIQUE slot part[bucket*1024+slot]; gp_reduce (24 blocks) sums
// buckets with exact counts (unused slots never read); no atomics anywhere.
// R9 recap: barrier-free one-wave 128x128 tile jobs, ALL global loads as
// opaque inline-asm global_load_dwordx4 + counted vmcnt + sched_barrier(0),
// p-terms baked into MFMA pad cols (MFMA out IS the exp2 arg), split-bf16
// 3-MFMA gram, xx/yy triangle symmetry, panel-major order, 8x1953 XCD swizzle.
//
// ws: Ah|Al|Bh|Bl [16][3968][32] bf16 (4 x 4,063,232 B) + acc[32] f32
//     + part[24*1024] f32.  total ~16.35 MB.

#define NP    3844
#define NPAD  3968
#define KP    32

#define W_XY  7688     // 8 * 31 * 31  xy wave-jobs
#define W_ALL 15624    // + 2 * 8 * 496 tri wave-jobs; 15624 = 8 * 1953
#define NBLK  15624

static constexpr float L_F   = 4.9475824173972215f;   // log2(e)/0.2916
static constexpr float C2L_F = 9.895164834794443f;    // 2*L

using bf16x8 = __attribute__((ext_vector_type(8))) short;
using f32x4  = __attribute__((ext_vector_type(4))) float;

#define MFMA16(a, b, c) __builtin_amdgcn_mfma_f32_16x16x32_bf16((a), (b), (c), 0, 0, 0)

__device__ inline unsigned short f2bf(float f) {
    union { float f; unsigned u; } v; v.f = f;
    unsigned r = v.u + 0x7FFFu + ((v.u >> 16) & 1u);   // RNE (no NaN inputs)
    return (unsigned short)(r >> 16);
}
__device__ inline float bf2f(unsigned short h) {
    union { unsigned u; float f; } v; v.u = ((unsigned)h) << 16;
    return v.f;
}
__device__ inline void pack_store(unsigned short* dst, const unsigned short* v) {
    uint4* d = (uint4*)dst;
#pragma unroll
    for (int q = 0; q < 4; ++q) {
        unsigned w0 = (unsigned)v[8 * q + 0] | ((unsigned)v[8 * q + 1] << 16);
        unsigned w1 = (unsigned)v[8 * q + 2] | ((unsigned)v[8 * q + 3] << 16);
        unsigned w2 = (unsigned)v[8 * q + 4] | ((unsigned)v[8 * q + 5] << 16);
        unsigned w3 = (unsigned)v[8 * q + 6] | ((unsigned)v[8 * q + 7] << 16);
        d[q] = make_uint4(w0, w1, w2, w3);
    }
}

// One thread per (im, patch). A-side scaled by 2L with p-cols; B-side plain.
__global__ __launch_bounds__(256) void gp_prep(const float* __restrict__ x,
                                               const float* __restrict__ y,
                                               unsigned short* __restrict__ Ah,
                                               unsigned short* __restrict__ Al,
                                               unsigned short* __restrict__ Bh,
                                               unsigned short* __restrict__ Bl) {
    int i = blockIdx.x * 256 + threadIdx.x;          // 16*NPAD = 63488
    if (i >= 16 * NPAD) return;
    int n = i % NPAD, im = i / NPAD;
    int b = im & 7;
    const float* src = (im >> 3) ? y : x;

    unsigned short hA[32], lA[32], hB[32], lB[32];
#pragma unroll
    for (int k = 0; k < 32; ++k) { hA[k] = 0; lA[k] = 0; hB[k] = 0; lB[k] = 0; }

    float sq = 0.0f;
    const bool valid = (n < NP);
    if (valid) {
        int r = n / 62, c = n % 62;
#pragma unroll
        for (int ch = 0; ch < 3; ++ch)
#pragma unroll
            for (int pr = 0; pr < 3; ++pr)
#pragma unroll
                for (int pc = 0; pc < 3; ++pc) {
                    int k = ch * 9 + pr * 3 + pc;
                    float v = src[(((b * 3 + ch) * 64) + r + pr) * 64 + (c + pc)];
                    unsigned short hb = f2bf(v);
                    hB[k] = hb; lB[k] = f2bf(v - bf2f(hb));
                    float sv = C2L_F * v;
                    unsigned short ha = f2bf(sv);
                    hA[k] = ha; lA[k] = f2bf(sv - bf2f(ha));
                    sq = fmaf(v, v, sq);
                }
    }
    // col 27: A = 2L (const), B = -sq/2 (pad: -1e30 -> exp2 -> 0)
    {
        unsigned short h = f2bf(C2L_F);
        hA[27] = h; lA[27] = f2bf(C2L_F - bf2f(h));
        float tb = valid ? -0.5f * sq : -1e30f;
        unsigned short hb = f2bf(tb);
        hB[27] = hb; lB[27] = f2bf(tb - bf2f(hb));
    }
    // col 28: A = -L*sq (pad: -1e30), B = 1
    {
        float pa = valid ? -L_F * sq : -1e30f;
        unsigned short ha = f2bf(pa);
        hA[28] = ha; lA[28] = f2bf(pa - bf2f(ha));
        hB[28] = f2bf(1.0f); lB[28] = 0;
    }

    pack_store(Ah + (size_t)i * KP, hA);
    pack_store(Al + (size_t)i * KP, lA);
    pack_store(Bh + (size_t)i * KP, hB);
    pack_store(Bl + (size_t)i * KP, lB);
}

// Opaque 16B global load with immediate offset: cannot be sunk or remat'd.
template<int OFF>
__device__ inline bf16x8 gload(const unsigned short* p) {
    bf16x8 r;
    asm volatile("global_load_dwordx4 %0, %1, off offset:%2"
                 : "=v"(r) : "v"(p), "i"(OFF));
    return r;
}

// 4 independent rg-chains sharing one B fragment, then 16 exp2+add.
#define GROUP(AH0, AH1, AH2, AH3, AL0, AL1, AL2, AL3, BHC, BLC)              \
    do {                                                                     \
        f32x4 g0 = {0.f, 0.f, 0.f, 0.f}, g1 = {0.f, 0.f, 0.f, 0.f};          \
        f32x4 g2 = {0.f, 0.f, 0.f, 0.f}, g3 = {0.f, 0.f, 0.f, 0.f};          \
        g0 = MFMA16(AL0, BHC, g0); g1 = MFMA16(AL1, BHC, g1);                \
        g2 = MFMA16(AL2, BHC, g2); g3 = MFMA16(AL3, BHC, g3);                \
        g0 = MFMA16(AH0, BLC, g0); g1 = MFMA16(AH1, BLC, g1);                \
        g2 = MFMA16(AH2, BLC, g2); g3 = MFMA16(AH3, BLC, g3);                \
        g0 = MFMA16(AH0, BHC, g0); g1 = MFMA16(AH1, BHC, g1);                \
        g2 = MFMA16(AH2, BHC, g2); g3 = MFMA16(AH3, BHC, g3);                \
        s0 += __builtin_amdgcn_exp2f(g0[0]); s1 += __builtin_amdgcn_exp2f(g0[1]); \
        s2 += __builtin_amdgcn_exp2f(g0[2]); s3 += __builtin_amdgcn_exp2f(g0[3]); \
        s0 += __builtin_amdgcn_exp2f(g1[0]); s1 += __builtin_amdgcn_exp2f(g1[1]); \
        s2 += __builtin_amdgcn_exp2f(g1[2]); s3 += __builtin_amdgcn_exp2f(g1[3]); \
        s0 += __builtin_amdgcn_exp2f(g2[0]); s1 += __builtin_amdgcn_exp2f(g2[1]); \
        s2 += __builtin_amdgcn_exp2f(g2[2]); s3 += __builtin_amdgcn_exp2f(g2[3]); \
        s0 += __builtin_amdgcn_exp2f(g3[0]); s1 += __builtin_amdgcn_exp2f(g3[1]); \
        s2 += __builtin_amdgcn_exp2f(g3[2]); s3 += __builtin_amdgcn_exp2f(g3[3]); \
    } while (0)

// step: issue next B pair (opaque), wait current pair (counted, tied via +v),
// then compute both rg halves against the current pair.
#define STEP_MID(BHC, BLC, BHN, BLN, PH, PL, OFFN)                           \
    do {                                                                     \
        BHN = gload<OFFN>(PH); BLN = gload<OFFN>(PL);                        \
        asm volatile("s_waitcnt vmcnt(2)" : "+v"(BHC), "+v"(BLC));           \
        __builtin_amdgcn_sched_barrier(0);                                   \
        GROUP(ah0, ah1, ah2, ah3, al0, al1, al2, al3, BHC, BLC);             \
        GROUP(ah4, ah5, ah6, ah7, al4, al5, al6, al7, BHC, BLC);             \
    } while (0)

#define STEP_LAST(BHC, BLC)                                                  \
    do {                                                                     \
        asm volatile("s_waitcnt vmcnt(0)" : "+v"(BHC), "+v"(BLC));           \
        __builtin_amdgcn_sched_barrier(0);                                   \
        GROUP(ah0, ah1, ah2, ah3, al0, al1, al2, al3, BHC, BLC);             \
        GROUP(ah4, ah5, ah6, ah7, al4, al5, al6, al7, BHC, BLC);             \
    } while (0)

__global__ __launch_bounds__(64, 4) void gp_pairs10(const unsigned short* __restrict__ Ah,
                                                    const unsigned short* __restrict__ Al,
                                                    const unsigned short* __restrict__ Bh,
                                                    const unsigned short* __restrict__ Bl,
                                                    float* __restrict__ part) {
    const int phys = blockIdx.x;
    const int w = (phys & 7) * 1953 + (phys >> 3);   // bijective, 15624 = 8*1953

    const int l = threadIdx.x & 63;
    const int l15 = l & 15, lhi = l >> 4;

    int type, b, bx, by, slot;
    float wt = 1.0f;
    if (w < W_XY) {
        type = 0; b = w / 961;
        int rr = w % 961; by = rr / 31; bx = rr % 31;
        slot = rr;
    } else {
        int v = w - W_XY;
        type = 1 + v / 3968;
        int r = v % 3968; b = r / 496; int t2 = r % 496;
        by = (int)((sqrtf(8.0f * (float)t2 + 1.0f) - 1.0f) * 0.5f);
        while ((by + 1) * (by + 2) / 2 <= t2) ++by;
        while (by * (by + 1) / 2 > t2) --by;
        bx = t2 - by * (by + 1) / 2;
        wt = (bx == by) ? 1.0f : 2.0f;
        slot = t2;
    }
    int imA, imB;
    if (type == 0)      { imA = b;     imB = 8 + b; }
    else if (type == 1) { imA = b;     imB = b;     }
    else                { imA = 8 + b; imB = 8 + b; }

    // base pointers (rg/cg 0-3 via offset 0..3072; 4-7 via +4096B base)
    const size_t eA = ((size_t)(imA * NPAD + bx * 128 + l15)) * KP + lhi * 8;
    const size_t eB = ((size_t)(imB * NPAD + by * 128 + l15)) * KP + lhi * 8;
    const unsigned short* pAh0 = Ah + eA;
    const unsigned short* pAl0 = Al + eA;
    const unsigned short* pAh4 = pAh0 + 2048;
    const unsigned short* pAl4 = pAl0 + 2048;
    const unsigned short* pBh0 = Bh + eB;
    const unsigned short* pBl0 = Bl + eB;
    const unsigned short* pBh4 = pBh0 + 2048;
    const unsigned short* pBl4 = pBl0 + 2048;

    // A fragments: 16 opaque loads, pinned for the whole job.
    bf16x8 ah0 = gload<0>(pAh0),    ah1 = gload<1024>(pAh0);
    bf16x8 ah2 = gload<2048>(pAh0), ah3 = gload<3072>(pAh0);
    bf16x8 ah4 = gload<0>(pAh4),    ah5 = gload<1024>(pAh4);
    bf16x8 ah6 = gload<2048>(pAh4), ah7 = gload<3072>(pAh4);
    bf16x8 al0 = gload<0>(pAl0),    al1 = gload<1024>(pAl0);
    bf16x8 al2 = gload<2048>(pAl0), al3 = gload<3072>(pAl0);
    bf16x8 al4 = gload<0>(pAl4),    al5 = gload<1024>(pAl4);
    bf16x8 al6 = gload<2048>(pAl4), al7 = gload<3072>(pAl4);

    // first B pair in flight before the A-wait
    bf16x8 bhA = gload<0>(pBh0), blA = gload<0>(pBl0);
    bf16x8 bhB, blB;

    // wait A (leave the 2 B loads outstanding), pin all 16 A regs
    asm volatile("s_waitcnt vmcnt(2)"
                 : "+v"(ah0), "+v"(ah1), "+v"(ah2), "+v"(ah3),
                   "+v"(ah4), "+v"(ah5), "+v"(ah6), "+v"(ah7),
                   "+v"(al0), "+v"(al1), "+v"(al2), "+v"(al3),
                   "+v"(al4), "+v"(al5), "+v"(al6), "+v"(al7));
    __builtin_amdgcn_sched_barrier(0);

    float s0 = 0.f, s1 = 0.f, s2 = 0.f, s3 = 0.f;

    STEP_MID(bhA, blA, bhB, blB, pBh0, pBl0, 1024);   // cg0 (issue cg1)
    STEP_MID(bhB, blB, bhA, blA, pBh0, pBl0, 2048);   // cg1 (issue cg2)
    STEP_MID(bhA, blA, bhB, blB, pBh0, pBl0, 3072);   // cg2 (issue cg3)
    STEP_MID(bhB, blB, bhA, blA, pBh4, pBl4, 0);      // cg3 (issue cg4)
    STEP_MID(bhA, blA, bhB, blB, pBh4, pBl4, 1024);   // cg4 (issue cg5)
    STEP_MID(bhB, blB, bhA, blA, pBh4, pBl4, 2048);   // cg5 (issue cg6)
    STEP_MID(bhA, blA, bhB, blB, pBh4, pBl4, 3072);   // cg6 (issue cg7)
    STEP_LAST(bhB, blB);                              // cg7

    float sacc = wt * ((s0 + s1) + (s2 + s3));

    // wave reduce, then ONE PLAIN STORE to a unique slot (no atomics)
#pragma unroll
    for (int o = 32; o > 0; o >>= 1) sacc += __shfl_down(sacc, o, 64);
    if (l == 0) part[(type * 8 + b) * 1024 + slot] = sacc;
}

// 24 blocks: block b sums its bucket's exact count of partials -> acc[b].
__global__ __launch_bounds__(256) void gp_reduce(const float* __restrict__ part,
                                                 float* __restrict__ acc) {
    const int bkt = blockIdx.x;
    const int cnt = (bkt < 8) ? 961 : 496;
    const float* p = part + bkt * 1024;
    float s = 0.0f;
    for (int i = threadIdx.x; i < cnt; i += 256) s += p[i];
#pragma unroll
    for (int o = 32; o > 0; o >>= 1) s += __shfl_down(s, o, 64);
    __shared__ float red[4];
    if ((threadIdx.x & 63) == 0) red[threadIdx.x >> 6] = s;
    __syncthreads();
    if (threadIdx.x == 0) acc[bkt] = (red[0] + red[1]) + (red[2] + red[3]);
}

__global__ void gp_final(const float* __restrict__ acc, float* __restrict__ out) {
    if (threadIdx.x == 0) {
        double s = 0.0;
        for (int b = 0; b < 8; ++b)
            s += -2.0 * (double)acc[b] + (double)acc[8 + b] + (double)acc[16 + b];
        out[0] = (float)(s / (8.0 * (double)NP * (double)NP));
    }
}

extern "C" void kernel_launch(void* const* d_in, const int* in_sizes, int n_in,
                              void* d_out, int out_size, void* d_ws, size_t ws_size,
                              hipStream_t stream) {
    const float* x = (const float*)d_in[0];
    const float* y = (const float*)d_in[1];
    const size_t MSZ = (size_t)16 * NPAD * KP;
    unsigned short* Ah = (unsigned short*)d_ws;
    unsigned short* Al = Ah + MSZ;
    unsigned short* Bh = Al + MSZ;
    unsigned short* Bl = Bh + MSZ;
    float* acc = (float*)(Bl + MSZ);
    float* part = acc + 32;

    gp_prep<<<(16 * NPAD) / 256, 256, 0, stream>>>(x, y, Ah, Al, Bh, Bl);
    gp_pairs10<<<NBLK, 64, 0, stream>>>(Ah, Al, Bh, Bl, part);
    gp_reduce<<<24, 256, 0, stream>>>(part, acc);
    gp_final<<<1, 1, 0, stream>>>(acc, (float*)d_out);
}